// Round 11
// baseline (333.564 us; speedup 1.0000x reference)
//
#include <hip/hip_runtime.h>

// y[e] = W2 . relu(W1 . concat(z[src[e]], z[dst[e]]) + b1) + b2
// N=50000, D=128, H=512, E=500000. Compute-bound: 131 GFLOP in GEMM1.
// R11 = R10 minus the 32-reg overdraft that spilled it.
//  - B (wave's 64h x 256k) in 128 VGPRs, loaded ONCE per block -> B-L2
//    traffic 2GB -> 250MB (8 tiles amortize), K-loop has zero VMEM.
//  - gather(t+1) issued AFTER the epilogue's acc->y reduce (acc dead ->
//    greg 32 never coexists with acc 64). Latency covered by ldsY write +
//    barrier + atomic (~300-600 cyc), not fully exposed.
//  - Peak live: K-loop 128+64+16+addr ~= 228 <= 256 (bounds(256,2));
//    post-epilogue 128+32+16+addr ~= 200. No spill expected.
// R7 bones: hy grid-split, 64x64 wave tile, padded STRA, atomicAdd combine.

typedef __bf16 bf16x8 __attribute__((ext_vector_type(8)));
typedef float f32x4 __attribute__((ext_vector_type(4)));

#define STRA 264   // 256 + 8 pad (ushort units)
#define NT 8       // 64-edge tiles per block

__device__ __forceinline__ unsigned short f2b(float f) {
    unsigned int u = __float_as_uint(f);
    u = (u + 0x7fffu + ((u >> 16) & 1u)) >> 16;   // RNE
    return (unsigned short)u;
}

// zb: z as bf16 [N][128].  w1s: W1 swizzled to MFMA-B fragment order:
// w1s[(hblk*8 + kc)*512 + lane*8 + t] = bf16(W1[hblk*16 + (lane&15)][kc*32 + (lane>>4)*8 + t])
// Also zeroes out[] (atomicAdd target).
__global__ void prep_kernel(const float* __restrict__ z, const float* __restrict__ W1,
                            unsigned short* __restrict__ zb, unsigned short* __restrict__ w1s,
                            float* __restrict__ outz, int nz4, int nout4) {
    int stride = gridDim.x * blockDim.x;
    const int nw = 256 * 64;   // (hblk*8+kc) x lane
    const int total = nz4 + nw + nout4;
    for (int idx = blockIdx.x * blockDim.x + threadIdx.x; idx < total; idx += stride) {
        if (idx < nz4) {
            float4 v = ((const float4*)z)[idx];
            ushort4 o;
            o.x = f2b(v.x); o.y = f2b(v.y); o.z = f2b(v.z); o.w = f2b(v.w);
            ((ushort4*)zb)[idx] = o;
        } else if (idx < nz4 + nw) {
            int u = idx - nz4;            // 0..16383
            int lane = u & 63;
            int blk  = u >> 6;            // hblk*8 + kc
            int h  = (blk >> 3) * 16 + (lane & 15);
            int kb = (blk & 7) * 32 + (lane >> 4) * 8;
            const float* src = W1 + h * 256 + kb;
            ushort4 o0, o1;
            float4 v0 = *(const float4*)(src);
            float4 v1 = *(const float4*)(src + 4);
            o0.x = f2b(v0.x); o0.y = f2b(v0.y); o0.z = f2b(v0.z); o0.w = f2b(v0.w);
            o1.x = f2b(v1.x); o1.y = f2b(v1.y); o1.z = f2b(v1.z); o1.w = f2b(v1.w);
            ushort4* dst = (ushort4*)(w1s + u * 8);
            dst[0] = o0; dst[1] = o1;
        } else {
            ((float4*)outz)[idx - nz4 - nw] = (float4){0.f, 0.f, 0.f, 0.f};
        }
    }
}

__global__ __launch_bounds__(256, 2)
void edge_mlp_kernel(const int* __restrict__ ei, const unsigned short* __restrict__ zb,
                     const unsigned short* __restrict__ w1s,
                     const float* __restrict__ b1, const float* __restrict__ W2,
                     const float* __restrict__ b2p, float* __restrict__ out, int E) {
    __shared__ unsigned short ldsA[64 * STRA];   // 33792 B, single buffer
    __shared__ int ldsIdx[2 * NT * 64];          // [side][512] : 4 KB
    __shared__ float ldsY[4 * 64];               // per-wave GEMM2 partials

    const int tid  = threadIdx.x;
    const int lane = tid & 63;
    const int w    = tid >> 6;        // 0..3 : 64-h slice within this hy half
    const int l15  = lane & 15;
    const int l4   = lane >> 4;
    const int g    = tid >> 4;        // gather group (16 groups)
    const int l    = tid & 15;        // gather lane-in-row
    const int hy   = blockIdx.x;      // 0..1 : which 256-h half of H
    const int t0e  = blockIdx.y * (NT * 64);   // first edge of this block

    // ---- preload B: wave's 64h x 256k as 32 bf16x8 fragments (128 VGPRs) ----
    bf16x8 breg[4][8];
    {
        const unsigned short* bb = w1s + ((hy * 16 + w * 4) * 8) * 512 + lane * 8;
        #pragma unroll
        for (int j = 0; j < 4; j++)
            #pragma unroll
            for (int kc = 0; kc < 8; kc++)
                breg[j][kc] = *(const bf16x8*)(bb + (j * 8 + kc) * 512);
    }

    // ---- preload all edge indices for the block's NT tiles ----
    #pragma unroll
    for (int k = 0; k < 4; k++) {
        int p = tid + k * 256;        // 0..1023 = side*512 + eo
        int side = p >> 9;
        int eo = p & 511;
        int e = t0e + eo;
        ldsIdx[p] = (e < E) ? ei[side * E + e] : 0;
    }
    __syncthreads();                  // ldsIdx ready

    // ---- gather tile 0 into registers ----
    uint4 greg[8];
    #pragma unroll
    for (int it = 0; it < 8; ++it) {
        int hr = it * 16 + g, m = hr >> 1, side = hr & 1;
        int row = ldsIdx[side * 512 + m];
        greg[it] = *((const uint4*)(zb + (row << 7)) + l);
    }

    const unsigned aoff = l15 * STRA + l4 * 8;

    #pragma unroll 1
    for (int t = 0; t < NT; ++t) {
        // stage tile t (greg -> ldsA); prior barrier guarantees ldsA is free
        #pragma unroll
        for (int it = 0; it < 8; ++it) {
            int hr = it * 16 + g, m = hr >> 1, side = hr & 1;
            *(uint4*)&ldsA[m * STRA + side * 128 + l * 8] = greg[it];
        }
        __syncthreads();              // barrier1: ldsA(t) visible

        // ---- K-loop: pure ds_read + MFMA (B from regs, zero VMEM) ----
        f32x4 acc[4][4];
        #pragma unroll
        for (int i = 0; i < 4; i++)
            #pragma unroll
            for (int j = 0; j < 4; j++) acc[i][j] = (f32x4){0.f, 0.f, 0.f, 0.f};

        #pragma unroll
        for (int kc = 0; kc < 8; ++kc) {
            bf16x8 a[4];
            #pragma unroll
            for (int i = 0; i < 4; i++)
                a[i] = *(const bf16x8*)&ldsA[aoff + i * 16 * STRA + kc * 32];
            #pragma unroll
            for (int i = 0; i < 4; i++)
                #pragma unroll
                for (int j = 0; j < 4; j++)
                    acc[i][j] = __builtin_amdgcn_mfma_f32_16x16x32_bf16(
                        a[i], breg[j][kc], acc[i][j], 0, 0, 0);
        }

        // ---- epilogue: h = relu(acc + b1); y = sum_h h * W2[h] (acc dies) ----
        float y[4][4];
        #pragma unroll
        for (int j = 0; j < 4; j++) {
            int h = hy * 256 + w * 64 + j * 16 + l15;
            float w2v = W2[h];
            float b1v = b1[h];
            #pragma unroll
            for (int i = 0; i < 4; i++)
                #pragma unroll
                for (int r = 0; r < 4; r++) {
                    float hv = acc[i][j][r] + b1v;
                    float s = fmaxf(hv, 0.f) * w2v;
                    y[i][r] = (j == 0) ? s : y[i][r] + s;
                }
        }
        #pragma unroll
        for (int i = 0; i < 4; i++)
            #pragma unroll
            for (int r = 0; r < 4; r++) {
                float v = y[i][r];
                v += __shfl_xor(v, 1);
                v += __shfl_xor(v, 2);
                v += __shfl_xor(v, 4);
                v += __shfl_xor(v, 8);
                y[i][r] = v;
            }

        // ---- issue gather(t+1) now: acc is dead, latency hides under
        //      ldsY write + barrier2 + atomic store ----
        if (t + 1 < NT) {
            #pragma unroll
            for (int it = 0; it < 8; ++it) {
                int hr = it * 16 + g, m = hr >> 1, side = hr & 1;
                int row = ldsIdx[side * 512 + (t + 1) * 64 + m];
                greg[it] = *((const uint4*)(zb + (row << 7)) + l);
            }
        }

        if (l15 == 0) {
            #pragma unroll
            for (int i = 0; i < 4; i++)
                #pragma unroll
                for (int r = 0; r < 4; r++) {
                    int m = i * 16 + l4 * 4 + r;   // C layout: row=(lane>>4)*4+reg
                    ldsY[w * 64 + m] = y[i][r];
                }
        }
        __syncthreads();              // barrier2: ldsY visible; all K-reads done -> ldsA free

        if (tid < 64) {
            int e = t0e + t * 64 + tid;
            if (e < E) {
                float v = ldsY[tid] + ldsY[64 + tid] + ldsY[128 + tid] + ldsY[192 + tid];
                if (hy == 0) v += b2p[0];
                atomicAdd(&out[e], v);   // exactly 2 addends per e -> order-safe
            }
        }
    }
}

extern "C" void kernel_launch(void* const* d_in, const int* in_sizes, int n_in,
                              void* d_out, int out_size, void* d_ws, size_t ws_size,
                              hipStream_t stream) {
    const float* z  = (const float*)d_in[0];
    const int*   ei = (const int*)d_in[1];
    const float* W1 = (const float*)d_in[2];
    const float* b1 = (const float*)d_in[3];
    const float* W2 = (const float*)d_in[4];
    const float* b2 = (const float*)d_in[5];
    float* out = (float*)d_out;

    const int E  = in_sizes[1] / 2;   // 500000
    const int NZ = in_sizes[0];       // 6400000 = N*D

    unsigned short* zb  = (unsigned short*)d_ws;       // 12.8 MB
    unsigned short* w1s = zb + NZ;                     // 256 KB (swizzled W1)

    prep_kernel<<<2048, 256, 0, stream>>>(z, W1, zb, w1s, out, NZ / 4, E / 4);

    const int tiles   = (E + 63) / 64;                 // 7813
    const int yblocks = (tiles + NT - 1) / NT;         // 977
    dim3 grid(2, yblocks);
    edge_mlp_kernel<<<grid, 256, 0, stream>>>(ei, zb, w1s, b1, W2, b2, out, E);
}